// Round 1
// baseline (757.812 us; speedup 1.0000x reference)
//
#include <hip/hip_runtime.h>
#include <math.h>

#define DM 512
#define NH 8
#define BS 1024
#define HIST 199
#define TT 200

__device__ __forceinline__ float dot8(const float4& a0, const float4& a1,
                                      const float4& b0, const float4& b1) {
  float p = a0.x * b0.x;
  p = fmaf(a0.y, b0.y, p);
  p = fmaf(a0.z, b0.z, p);
  p = fmaf(a0.w, b0.w, p);
  p = fmaf(a1.x, b1.x, p);
  p = fmaf(a1.y, b1.y, p);
  p = fmaf(a1.z, b1.z, p);
  p = fmaf(a1.w, b1.w, p);
  return p;
}

__device__ __forceinline__ float wred64(float p) {
  p += __shfl_xor(p, 1);
  p += __shfl_xor(p, 2);
  p += __shfl_xor(p, 4);
  p += __shfl_xor(p, 8);
  p += __shfl_xor(p, 16);
  p += __shfl_xor(p, 32);
  return p;
}

// ---------------------------------------------------------------------------
// Kernel A1: q[b,j] = current[b,:] . Wq[j,:] + bq[j]
// grid 1024 = 256 b-groups x 4 j-quarters; 4 waves, wave w -> b = 4*bg + w.
// Lane-parallel dot over f (512) + butterfly reduce; Wq rows shared by the
// 4 waves (L1 hit).
// ---------------------------------------------------------------------------
__global__ __launch_bounds__(256, 4) void qproj_kernel(
    const float* __restrict__ cur, const float* __restrict__ Wq,
    const float* __restrict__ bq, float* __restrict__ q) {
  const int lane = threadIdx.x & 63;
  const int wave = threadIdx.x >> 6;
  const int b = (blockIdx.x >> 2) * 4 + wave;
  const int j0 = (blockIdx.x & 3) * 128;
  const float* cp = cur + (size_t)b * DM;
  const float4 ca = *(const float4*)(cp + 4 * lane);
  const float4 cb = *(const float4*)(cp + 256 + 4 * lane);
  float keep0 = 0.f, keep1 = 0.f;
  for (int jj = 0; jj < 128; ++jj) {
    const float* wp = Wq + (size_t)(j0 + jj) * DM;
    const float4 wa = *(const float4*)(wp + 4 * lane);
    const float4 wb = *(const float4*)(wp + 256 + 4 * lane);
    float p = wred64(dot8(ca, cb, wa, wb));
    if (jj < 64) {
      if (lane == jj) keep0 = p;
    } else {
      if (lane == (jj - 64)) keep1 = p;
    }
  }
  q[(size_t)b * DM + j0 + lane] = keep0 + bq[j0 + lane];
  q[(size_t)b * DM + j0 + 64 + lane] = keep1 + bq[j0 + 64 + lane];
}

// ---------------------------------------------------------------------------
// Kernel A2: qk1[b,h,e] = (sum_d q[b,h*64+d] * Wk[h*64+d, e]) / 8
//            qc1[b,h]   = (sum_d q[b,h*64+d] * bk[h*64+d]) / 8
// grid 1024 = 128 b-groups(8 b) x 8 h; 256 threads, thread -> e and e+256.
// Wk reads coalesced over e; q slice staged in LDS, broadcast reads.
// ---------------------------------------------------------------------------
__global__ __launch_bounds__(256, 4) void qk_kernel(
    const float* __restrict__ q, const float* __restrict__ Wk,
    const float* __restrict__ bk, float* __restrict__ qk1,
    float* __restrict__ qc1) {
  __shared__ float q8[8][64];
  const int tid = threadIdx.x;
  const int bg = blockIdx.x >> 3;
  const int h = blockIdx.x & 7;
  for (int i = tid; i < 512; i += 256) {
    const int bl = i >> 6, d = i & 63;
    q8[bl][d] = q[(size_t)(bg * 8 + bl) * DM + h * 64 + d];
  }
  __syncthreads();
  float acc0[8], acc1[8];
#pragma unroll
  for (int bl = 0; bl < 8; ++bl) {
    acc0[bl] = 0.f;
    acc1[bl] = 0.f;
  }
  const int e = tid;
  const float* wkb = Wk + (size_t)h * 64 * DM;
  for (int d4 = 0; d4 < 64; d4 += 4) {
    float w0[4], w1[4];
#pragma unroll
    for (int dd = 0; dd < 4; ++dd) {
      w0[dd] = wkb[(size_t)(d4 + dd) * DM + e];
      w1[dd] = wkb[(size_t)(d4 + dd) * DM + e + 256];
    }
#pragma unroll
    for (int bl = 0; bl < 8; ++bl) {
      const float4 qq = *(const float4*)&q8[bl][d4];
      acc0[bl] = fmaf(qq.x, w0[0], acc0[bl]);
      acc0[bl] = fmaf(qq.y, w0[1], acc0[bl]);
      acc0[bl] = fmaf(qq.z, w0[2], acc0[bl]);
      acc0[bl] = fmaf(qq.w, w0[3], acc0[bl]);
      acc1[bl] = fmaf(qq.x, w1[0], acc1[bl]);
      acc1[bl] = fmaf(qq.y, w1[1], acc1[bl]);
      acc1[bl] = fmaf(qq.z, w1[2], acc1[bl]);
      acc1[bl] = fmaf(qq.w, w1[3], acc1[bl]);
    }
  }
#pragma unroll
  for (int bl = 0; bl < 8; ++bl) {
    const size_t base = ((size_t)(bg * 8 + bl) * NH + h) * DM;
    qk1[base + e] = acc0[bl] * 0.125f;
    qk1[base + e + 256] = acc1[bl] * 0.125f;
  }
  if (tid < 8) {
    float s = 0.f;
    for (int d = 0; d < 64; ++d) s += q8[tid][d] * bk[h * 64 + d];
    qc1[(size_t)(bg * 8 + tid) * NH + h] = s * 0.125f;
  }
}

// ---------------------------------------------------------------------------
// Kernel B: one block per batch b; 8 waves = 2 head-halves x 4 t-chunks(50).
// Per t: coalesced float4 row load (each row read by exactly 2 waves -> L1),
// 4 lane-parallel dots + butterfly reduce, exp (no max needed: |s| small),
// exp-weighted embedding accumulation in registers. LDS reduce over chunks,
// then fused Wv projection (Wv rows from L2) with coalesced store.
// ---------------------------------------------------------------------------
__global__ __launch_bounds__(512, 4) void attn_kernel(
    const float* __restrict__ cur, const float* __restrict__ prev,
    const float* __restrict__ mask, const float* __restrict__ qk1,
    const float* __restrict__ qc1, const float* __restrict__ Wv,
    const float* __restrict__ bv, float* __restrict__ out) {
  __shared__ float cbuf[2][4][4][DM];  // [g][c][hl][e] partial ctx, 64 KB
  __shared__ float lbuf[2][4][4];      // partial exp-sums
  const int tid = threadIdx.x;
  const int lane = tid & 63;
  const int wave = tid >> 6;
  const int g = wave & 1;   // head-half: heads [4g, 4g+4)
  const int c = wave >> 1;  // t-chunk: [50c, 50c+50)
  const int b = blockIdx.x;

  float4 ka[4], kb[4];
  float qc[4];
#pragma unroll
  for (int hl = 0; hl < 4; ++hl) {
    const float* kp = qk1 + ((size_t)b * NH + (g * 4 + hl)) * DM;
    ka[hl] = *(const float4*)(kp + 4 * lane);
    kb[hl] = *(const float4*)(kp + 256 + 4 * lane);
    qc[hl] = qc1[(size_t)b * NH + (g * 4 + hl)];
  }
  float4 cA[4], cB[4];
#pragma unroll
  for (int hl = 0; hl < 4; ++hl) {
    cA[hl] = make_float4(0.f, 0.f, 0.f, 0.f);
    cB[hl] = make_float4(0.f, 0.f, 0.f, 0.f);
  }
  float ls0 = 0.f, ls1 = 0.f, ls2 = 0.f, ls3 = 0.f;
  const float* mrow = mask + (size_t)b * TT;
  const int t0 = c * 50;
#pragma unroll 2
  for (int t = t0; t < t0 + 50; ++t) {
    const float* rowp = (t < HIST) ? (prev + ((size_t)b * HIST + t) * DM)
                                   : (cur + (size_t)b * DM);
    const float4 ra = *(const float4*)(rowp + 4 * lane);
    const float4 rb = *(const float4*)(rowp + 256 + 4 * lane);
    float pp[4];
#pragma unroll
    for (int hl = 0; hl < 4; ++hl) pp[hl] = dot8(ra, rb, ka[hl], kb[hl]);
#pragma unroll
    for (int hl = 0; hl < 4; ++hl) pp[hl] = wred64(pp[hl]);
    const float mval = mrow[t];
#pragma unroll
    for (int hl = 0; hl < 4; ++hl) {
      const float w = __expf(pp[hl] + qc[hl] + mval);
      if (hl == 0) ls0 += w;
      if (hl == 1) ls1 += w;
      if (hl == 2) ls2 += w;
      if (hl == 3) ls3 += w;
      cA[hl].x = fmaf(w, ra.x, cA[hl].x);
      cA[hl].y = fmaf(w, ra.y, cA[hl].y);
      cA[hl].z = fmaf(w, ra.z, cA[hl].z);
      cA[hl].w = fmaf(w, ra.w, cA[hl].w);
      cB[hl].x = fmaf(w, rb.x, cB[hl].x);
      cB[hl].y = fmaf(w, rb.y, cB[hl].y);
      cB[hl].z = fmaf(w, rb.z, cB[hl].z);
      cB[hl].w = fmaf(w, rb.w, cB[hl].w);
    }
  }
#pragma unroll
  for (int hl = 0; hl < 4; ++hl) {
    *(float4*)&cbuf[g][c][hl][4 * lane] = cA[hl];
    *(float4*)&cbuf[g][c][hl][256 + 4 * lane] = cB[hl];
  }
  if (lane == 0) {
    lbuf[g][c][0] = ls0;
    lbuf[g][c][1] = ls1;
    lbuf[g][c][2] = ls2;
    lbuf[g][c][3] = ls3;
  }
  __syncthreads();
  // Reduce over the 4 t-chunks; thread owns (gh, e0..e0+7).
  const int gh = tid >> 6;
  const int g2 = gh >> 2, h2 = gh & 3;
  const int e0 = (tid & 63) * 8;
  float s0[8];
#pragma unroll
  for (int k = 0; k < 8; ++k) s0[k] = 0.f;
#pragma unroll
  for (int cc = 0; cc < 4; ++cc) {
    const float4 a = *(const float4*)&cbuf[g2][cc][h2][e0];
    const float4 bb = *(const float4*)&cbuf[g2][cc][h2][e0 + 4];
    s0[0] += a.x;
    s0[1] += a.y;
    s0[2] += a.z;
    s0[3] += a.w;
    s0[4] += bb.x;
    s0[5] += bb.y;
    s0[6] += bb.z;
    s0[7] += bb.w;
  }
  const float inv = 1.0f / (lbuf[g2][0][h2] + lbuf[g2][1][h2] +
                            lbuf[g2][2][h2] + lbuf[g2][3][h2]);
  __syncthreads();
  // cn[8][512] aliased into the first 16 KB of cbuf (safe: all reads done).
  float* cn = &cbuf[0][0][0][0];
  *(float4*)(cn + (size_t)gh * DM + e0) =
      make_float4(s0[0] * inv, s0[1] * inv, s0[2] * inv, s0[3] * inv);
  *(float4*)(cn + (size_t)gh * DM + e0 + 4) =
      make_float4(s0[4] * inv, s0[5] * inv, s0[6] * inv, s0[7] * inv);
  __syncthreads();
  // Out projection: wave w -> head hh = w, output rows [64w, 64w+64).
  const int hh = wave;
  const float4 na = *(const float4*)(cn + (size_t)hh * DM + 4 * lane);
  const float4 nb = *(const float4*)(cn + (size_t)hh * DM + 256 + 4 * lane);
  float keep = 0.f;
  for (int r = 0; r < 64; ++r) {
    const float* wvp = Wv + (size_t)(hh * 64 + r) * DM;
    const float4 wa = *(const float4*)(wvp + 4 * lane);
    const float4 wb = *(const float4*)(wvp + 256 + 4 * lane);
    float p = wred64(dot8(na, nb, wa, wb));
    if (lane == r) keep = p;
  }
  out[(size_t)b * DM + hh * 64 + lane] = keep + bv[hh * 64 + lane];
}

extern "C" void kernel_launch(void* const* d_in, const int* in_sizes, int n_in,
                              void* d_out, int out_size, void* d_ws,
                              size_t ws_size, hipStream_t stream) {
  const float* cur = (const float*)d_in[0];   // [1024, 512]
  const float* prev = (const float*)d_in[1];  // [1024, 199, 512]
  const float* mask = (const float*)d_in[2];  // [1024, 200]
  const float* Wq = (const float*)d_in[3];    // [512, 512]
  const float* bq = (const float*)d_in[4];    // [512]
  const float* Wk = (const float*)d_in[5];
  const float* bk = (const float*)d_in[6];
  const float* Wv = (const float*)d_in[7];
  const float* bv = (const float*)d_in[8];
  float* out = (float*)d_out;  // [1024, 512] fp32

  // workspace: q [1024*512] | qk1 [1024*8*512] | qc1 [1024*8]  (~18.9 MB)
  float* q = (float*)d_ws;
  float* qk1 = q + (size_t)BS * DM;
  float* qc1 = qk1 + (size_t)BS * NH * DM;

  qproj_kernel<<<1024, 256, 0, stream>>>(cur, Wq, bq, q);
  qk_kernel<<<1024, 256, 0, stream>>>(q, Wk, bk, qk1, qc1);
  attn_kernel<<<1024, 512, 0, stream>>>(cur, prev, mask, qk1, qc1, Wv, bv, out);
}

// Round 2
// 716.969 us; speedup vs baseline: 1.0570x; 1.0570x over previous
//
#include <hip/hip_runtime.h>
#include <math.h>

#define DM 512
#define NH 8
#define BS 1024
#define HIST 199
#define TT 200

__device__ __forceinline__ float dot8(const float4& a0, const float4& a1,
                                      const float4& b0, const float4& b1) {
  float p = a0.x * b0.x;
  p = fmaf(a0.y, b0.y, p);
  p = fmaf(a0.z, b0.z, p);
  p = fmaf(a0.w, b0.w, p);
  p = fmaf(a1.x, b1.x, p);
  p = fmaf(a1.y, b1.y, p);
  p = fmaf(a1.z, b1.z, p);
  p = fmaf(a1.w, b1.w, p);
  return p;
}

__device__ __forceinline__ float wred64(float p) {
  p += __shfl_xor(p, 1);
  p += __shfl_xor(p, 2);
  p += __shfl_xor(p, 4);
  p += __shfl_xor(p, 8);
  p += __shfl_xor(p, 16);
  p += __shfl_xor(p, 32);
  return p;
}

// ---------------------------------------------------------------------------
// Kernel A1: q[b,j] = current[b,:] . Wq[j,:] + bq[j]
// grid 1024 = 256 b-groups x 4 j-quarters; 4 waves, wave w -> b = 4*bg + w.
// ---------------------------------------------------------------------------
__global__ __launch_bounds__(256, 4) void qproj_kernel(
    const float* __restrict__ cur, const float* __restrict__ Wq,
    const float* __restrict__ bq, float* __restrict__ q) {
  const int lane = threadIdx.x & 63;
  const int wave = threadIdx.x >> 6;
  const int b = (blockIdx.x >> 2) * 4 + wave;
  const int j0 = (blockIdx.x & 3) * 128;
  const float* cp = cur + (size_t)b * DM;
  const float4 ca = *(const float4*)(cp + 4 * lane);
  const float4 cb = *(const float4*)(cp + 256 + 4 * lane);
  float keep0 = 0.f, keep1 = 0.f;
  for (int jj = 0; jj < 128; ++jj) {
    const float* wp = Wq + (size_t)(j0 + jj) * DM;
    const float4 wa = *(const float4*)(wp + 4 * lane);
    const float4 wb = *(const float4*)(wp + 256 + 4 * lane);
    float p = wred64(dot8(ca, cb, wa, wb));
    if (jj < 64) {
      if (lane == jj) keep0 = p;
    } else {
      if (lane == (jj - 64)) keep1 = p;
    }
  }
  q[(size_t)b * DM + j0 + lane] = keep0 + bq[j0 + lane];
  q[(size_t)b * DM + j0 + 64 + lane] = keep1 + bq[j0 + 64 + lane];
}

// ---------------------------------------------------------------------------
// Kernel A2: qk1[b,h,e] = (sum_d q[b,h*64+d] * Wk[h*64+d, e]) / 8
//            qc1[b,h]   = (sum_d q[b,h*64+d] * bk[h*64+d]) / 8
// ---------------------------------------------------------------------------
__global__ __launch_bounds__(256, 4) void qk_kernel(
    const float* __restrict__ q, const float* __restrict__ Wk,
    const float* __restrict__ bk, float* __restrict__ qk1,
    float* __restrict__ qc1) {
  __shared__ float q8[8][64];
  const int tid = threadIdx.x;
  const int bg = blockIdx.x >> 3;
  const int h = blockIdx.x & 7;
  for (int i = tid; i < 512; i += 256) {
    const int bl = i >> 6, d = i & 63;
    q8[bl][d] = q[(size_t)(bg * 8 + bl) * DM + h * 64 + d];
  }
  __syncthreads();
  float acc0[8], acc1[8];
#pragma unroll
  for (int bl = 0; bl < 8; ++bl) {
    acc0[bl] = 0.f;
    acc1[bl] = 0.f;
  }
  const int e = tid;
  const float* wkb = Wk + (size_t)h * 64 * DM;
  for (int d4 = 0; d4 < 64; d4 += 4) {
    float w0[4], w1[4];
#pragma unroll
    for (int dd = 0; dd < 4; ++dd) {
      w0[dd] = wkb[(size_t)(d4 + dd) * DM + e];
      w1[dd] = wkb[(size_t)(d4 + dd) * DM + e + 256];
    }
#pragma unroll
    for (int bl = 0; bl < 8; ++bl) {
      const float4 qq = *(const float4*)&q8[bl][d4];
      acc0[bl] = fmaf(qq.x, w0[0], acc0[bl]);
      acc0[bl] = fmaf(qq.y, w0[1], acc0[bl]);
      acc0[bl] = fmaf(qq.z, w0[2], acc0[bl]);
      acc0[bl] = fmaf(qq.w, w0[3], acc0[bl]);
      acc1[bl] = fmaf(qq.x, w1[0], acc1[bl]);
      acc1[bl] = fmaf(qq.y, w1[1], acc1[bl]);
      acc1[bl] = fmaf(qq.z, w1[2], acc1[bl]);
      acc1[bl] = fmaf(qq.w, w1[3], acc1[bl]);
    }
  }
#pragma unroll
  for (int bl = 0; bl < 8; ++bl) {
    const size_t base = ((size_t)(bg * 8 + bl) * NH + h) * DM;
    qk1[base + e] = acc0[bl] * 0.125f;
    qk1[base + e + 256] = acc1[bl] * 0.125f;
  }
  if (tid < 8) {
    float s = 0.f;
    for (int d = 0; d < 64; ++d) s += q8[tid][d] * bk[h * 64 + d];
    qc1[(size_t)(bg * 8 + tid) * NH + h] = s * 0.125f;
  }
}

// ---------------------------------------------------------------------------
// Kernel B: one block per batch b; 8 waves = 2 head-halves x 4 t-chunks(50).
// v2: mask preloaded to a register + __shfl broadcast (no per-t s_load ->
// no lgkmcnt(0) pipeline drains); explicit row prefetch (t+1 loads issued
// before t's reduction chain); staged cross-chunk LDS reduce (16.6 KB LDS
// instead of 64 KB).
// ---------------------------------------------------------------------------
__global__ __launch_bounds__(512, 4) void attn_kernel(
    const float* __restrict__ cur, const float* __restrict__ prev,
    const float* __restrict__ mask, const float* __restrict__ qk1,
    const float* __restrict__ qc1, const float* __restrict__ Wv,
    const float* __restrict__ bv, float* __restrict__ out) {
  __shared__ float red[2][4][DM];  // [g][hl][e] staged ctx reduce, 16 KB
  __shared__ float lred[2][4][4];  // [g][c][hl] exp-sum partials
  const int tid = threadIdx.x;
  const int lane = tid & 63;
  const int wave = tid >> 6;
  const int g = wave & 1;   // head-half: heads [4g, 4g+4)
  const int c = wave >> 1;  // t-chunk: [50c, 50c+50)
  const int b = blockIdx.x;

  float4 ka[4], kb[4];
  float qc[4];
#pragma unroll
  for (int hl = 0; hl < 4; ++hl) {
    const float* kp = qk1 + ((size_t)b * NH + (g * 4 + hl)) * DM;
    ka[hl] = *(const float4*)(kp + 4 * lane);
    kb[hl] = *(const float4*)(kp + 256 + 4 * lane);
    qc[hl] = qc1[(size_t)b * NH + (g * 4 + hl)];
  }
  float4 cA[4], cB[4];
#pragma unroll
  for (int hl = 0; hl < 4; ++hl) {
    cA[hl] = make_float4(0.f, 0.f, 0.f, 0.f);
    cB[hl] = make_float4(0.f, 0.f, 0.f, 0.f);
  }
  float ls0 = 0.f, ls1 = 0.f, ls2 = 0.f, ls3 = 0.f;
  const int t0 = c * 50;
  // Preload this chunk's 50 mask values into one reg/lane (vector load, no
  // per-t scalar loads in the hot loop). Clamp lanes 50..63 to stay in-bounds.
  const int ml = (lane < 49) ? lane : 49;
  const float mreg = mask[(size_t)b * TT + t0 + ml];

  // Prefetch-rotated row loop.
  const float* rp0 = (t0 < HIST) ? (prev + ((size_t)b * HIST + t0) * DM)
                                 : (cur + (size_t)b * DM);
  float4 ra = *(const float4*)(rp0 + 4 * lane);
  float4 rb = *(const float4*)(rp0 + 256 + 4 * lane);
  for (int t = t0; t < t0 + 50; ++t) {
    // issue next row's loads before this row's reduction chain
    int tn = t + 1;
    if (tn >= t0 + 50) tn = t0 + 49;
    const float* np = (tn < HIST) ? (prev + ((size_t)b * HIST + tn) * DM)
                                  : (cur + (size_t)b * DM);
    const float4 nra = *(const float4*)(np + 4 * lane);
    const float4 nrb = *(const float4*)(np + 256 + 4 * lane);

    float pp[4];
#pragma unroll
    for (int hl = 0; hl < 4; ++hl) pp[hl] = dot8(ra, rb, ka[hl], kb[hl]);
#pragma unroll
    for (int hl = 0; hl < 4; ++hl) pp[hl] = wred64(pp[hl]);
    const float mval = __shfl(mreg, t - t0);  // v_readlane, no lgkm wait
#pragma unroll
    for (int hl = 0; hl < 4; ++hl) {
      const float w = __expf(pp[hl] + qc[hl] + mval);
      if (hl == 0) ls0 += w;
      if (hl == 1) ls1 += w;
      if (hl == 2) ls2 += w;
      if (hl == 3) ls3 += w;
      cA[hl].x = fmaf(w, ra.x, cA[hl].x);
      cA[hl].y = fmaf(w, ra.y, cA[hl].y);
      cA[hl].z = fmaf(w, ra.z, cA[hl].z);
      cA[hl].w = fmaf(w, ra.w, cA[hl].w);
      cB[hl].x = fmaf(w, rb.x, cB[hl].x);
      cB[hl].y = fmaf(w, rb.y, cB[hl].y);
      cB[hl].z = fmaf(w, rb.z, cB[hl].z);
      cB[hl].w = fmaf(w, rb.w, cB[hl].w);
    }
    ra = nra;
    rb = nrb;
  }
  if (lane == 0) {
    lred[g][c][0] = ls0;
    lred[g][c][1] = ls1;
    lred[g][c][2] = ls2;
    lred[g][c][3] = ls3;
  }
  // Staged reduction over the 4 t-chunks into red[g][hl][e].
  for (int cc = 0; cc < 4; ++cc) {
    if (c == cc) {
#pragma unroll
      for (int hl = 0; hl < 4; ++hl) {
        float* dst = &red[g][hl][0];
        if (cc == 0) {
          *(float4*)(dst + 4 * lane) = cA[hl];
          *(float4*)(dst + 256 + 4 * lane) = cB[hl];
        } else {
          float4 o0 = *(const float4*)(dst + 4 * lane);
          float4 o1 = *(const float4*)(dst + 256 + 4 * lane);
          o0.x += cA[hl].x;
          o0.y += cA[hl].y;
          o0.z += cA[hl].z;
          o0.w += cA[hl].w;
          o1.x += cB[hl].x;
          o1.y += cB[hl].y;
          o1.z += cB[hl].z;
          o1.w += cB[hl].w;
          *(float4*)(dst + 4 * lane) = o0;
          *(float4*)(dst + 256 + 4 * lane) = o1;
        }
      }
    }
    __syncthreads();
  }
  // Out projection: wave hh -> head hh, output rows [64*hh, 64*hh+64).
  // out = (ctx_unnorm . Wv_row) * (1/sum_exp) + bv  (linearity lets us defer
  // the softmax normalization to one scalar multiply at the end).
  const int hh = wave;
  const int g2 = hh >> 2, h2 = hh & 3;
  const float linv = 1.0f / (lred[g2][0][h2] + lred[g2][1][h2] +
                             lred[g2][2][h2] + lred[g2][3][h2]);
  const float4 na = *(const float4*)(&red[g2][h2][0] + 4 * lane);
  const float4 nb = *(const float4*)(&red[g2][h2][0] + 256 + 4 * lane);
  float keep = 0.f;
  for (int r = 0; r < 64; ++r) {
    const float* wvp = Wv + (size_t)(hh * 64 + r) * DM;
    const float4 wa = *(const float4*)(wvp + 4 * lane);
    const float4 wb = *(const float4*)(wvp + 256 + 4 * lane);
    float p = wred64(dot8(na, nb, wa, wb));
    if (lane == r) keep = p;
  }
  out[(size_t)b * DM + hh * 64 + lane] = keep * linv + bv[hh * 64 + lane];
}

extern "C" void kernel_launch(void* const* d_in, const int* in_sizes, int n_in,
                              void* d_out, int out_size, void* d_ws,
                              size_t ws_size, hipStream_t stream) {
  const float* cur = (const float*)d_in[0];   // [1024, 512]
  const float* prev = (const float*)d_in[1];  // [1024, 199, 512]
  const float* mask = (const float*)d_in[2];  // [1024, 200]
  const float* Wq = (const float*)d_in[3];    // [512, 512]
  const float* bq = (const float*)d_in[4];    // [512]
  const float* Wk = (const float*)d_in[5];
  const float* bk = (const float*)d_in[6];
  const float* Wv = (const float*)d_in[7];
  const float* bv = (const float*)d_in[8];
  float* out = (float*)d_out;  // [1024, 512] fp32

  // workspace: q [1024*512] | qk1 [1024*8*512] | qc1 [1024*8]  (~18.9 MB)
  float* q = (float*)d_ws;
  float* qk1 = q + (size_t)BS * DM;
  float* qc1 = qk1 + (size_t)BS * NH * DM;

  qproj_kernel<<<1024, 256, 0, stream>>>(cur, Wq, bq, q);
  qk_kernel<<<1024, 256, 0, stream>>>(q, Wk, bk, qk1, qc1);
  attn_kernel<<<1024, 512, 0, stream>>>(cur, prev, mask, qk1, qc1, Wv, bv, out);
}

// Round 3
// 681.010 us; speedup vs baseline: 1.1128x; 1.0528x over previous
//
#include <hip/hip_runtime.h>
#include <math.h>

#define DM 512
#define NH 8
#define BS 1024
#define HIST 199
#define TT 200

__device__ __forceinline__ float dot8(const float4& a0, const float4& a1,
                                      const float4& b0, const float4& b1) {
  float p = a0.x * b0.x;
  p = fmaf(a0.y, b0.y, p);
  p = fmaf(a0.z, b0.z, p);
  p = fmaf(a0.w, b0.w, p);
  p = fmaf(a1.x, b1.x, p);
  p = fmaf(a1.y, b1.y, p);
  p = fmaf(a1.z, b1.z, p);
  p = fmaf(a1.w, b1.w, p);
  return p;
}

__device__ __forceinline__ float wred64(float p) {
  p += __shfl_xor(p, 1);
  p += __shfl_xor(p, 2);
  p += __shfl_xor(p, 4);
  p += __shfl_xor(p, 8);
  p += __shfl_xor(p, 16);
  p += __shfl_xor(p, 32);
  return p;
}

// ---------------------------------------------------------------------------
// Kernel A1 v3: q[b,j] = current[b,:] . Wq[j,:] + bq[j]
// grid 1024 = 256 b-groups(4 b) x 4 j-quarters; wave w -> 32 distinct rows
// j0 = jq*128 + w*32, each dotted against 4 batches' cur held in registers.
// Each Wq row loaded ONCE per block (was 4x) -> L1 traffic /4.
// ---------------------------------------------------------------------------
__global__ __launch_bounds__(256, 4) void qproj_kernel(
    const float* __restrict__ cur, const float* __restrict__ Wq,
    const float* __restrict__ bq, float* __restrict__ q) {
  const int lane = threadIdx.x & 63;
  const int wave = threadIdx.x >> 6;
  const int bg = blockIdx.x >> 2;
  const int jq = blockIdx.x & 3;
  const int j0 = jq * 128 + wave * 32;
  float4 ca[4], cb[4];
#pragma unroll
  for (int bb = 0; bb < 4; ++bb) {
    const float* cp = cur + (size_t)(bg * 4 + bb) * DM;
    ca[bb] = *(const float4*)(cp + 4 * lane);
    cb[bb] = *(const float4*)(cp + 256 + 4 * lane);
  }
  float keep[2] = {0.f, 0.f};
  for (int r = 0; r < 32; ++r) {
    const float* wp = Wq + (size_t)(j0 + r) * DM;
    const float4 wa = *(const float4*)(wp + 4 * lane);
    const float4 wb = *(const float4*)(wp + 256 + 4 * lane);
    float pp[4];
#pragma unroll
    for (int bb = 0; bb < 4; ++bb)
      pp[bb] = wred64(dot8(ca[bb], cb[bb], wa, wb));
    // result (bb, r) kept by lane (bb&1)*32 + r in slot bb>>1
#pragma unroll
    for (int bb = 0; bb < 4; ++bb)
      if (lane == ((bb & 1) * 32 + r)) keep[bb >> 1] = pp[bb];
  }
  const int r = lane & 31, bh = lane >> 5;
  const int j = j0 + r;
#pragma unroll
  for (int s = 0; s < 2; ++s) {
    const int b = bg * 4 + 2 * s + bh;
    q[(size_t)b * DM + j] = keep[s] + bq[j];
  }
}

// ---------------------------------------------------------------------------
// Kernel A2: qk1[b,h,e] = (sum_d q[b,h*64+d] * Wk[h*64+d, e]) / 8
//            qc1[b,h]   = (sum_d q[b,h*64+d] * bk[h*64+d]) / 8
// ---------------------------------------------------------------------------
__global__ __launch_bounds__(256, 4) void qk_kernel(
    const float* __restrict__ q, const float* __restrict__ Wk,
    const float* __restrict__ bk, float* __restrict__ qk1,
    float* __restrict__ qc1) {
  __shared__ float q8[8][64];
  const int tid = threadIdx.x;
  const int bg = blockIdx.x >> 3;
  const int h = blockIdx.x & 7;
  for (int i = tid; i < 512; i += 256) {
    const int bl = i >> 6, d = i & 63;
    q8[bl][d] = q[(size_t)(bg * 8 + bl) * DM + h * 64 + d];
  }
  __syncthreads();
  float acc0[8], acc1[8];
#pragma unroll
  for (int bl = 0; bl < 8; ++bl) {
    acc0[bl] = 0.f;
    acc1[bl] = 0.f;
  }
  const int e = tid;
  const float* wkb = Wk + (size_t)h * 64 * DM;
  for (int d4 = 0; d4 < 64; d4 += 4) {
    float w0[4], w1[4];
#pragma unroll
    for (int dd = 0; dd < 4; ++dd) {
      w0[dd] = wkb[(size_t)(d4 + dd) * DM + e];
      w1[dd] = wkb[(size_t)(d4 + dd) * DM + e + 256];
    }
#pragma unroll
    for (int bl = 0; bl < 8; ++bl) {
      const float4 qq = *(const float4*)&q8[bl][d4];
      acc0[bl] = fmaf(qq.x, w0[0], acc0[bl]);
      acc0[bl] = fmaf(qq.y, w0[1], acc0[bl]);
      acc0[bl] = fmaf(qq.z, w0[2], acc0[bl]);
      acc0[bl] = fmaf(qq.w, w0[3], acc0[bl]);
      acc1[bl] = fmaf(qq.x, w1[0], acc1[bl]);
      acc1[bl] = fmaf(qq.y, w1[1], acc1[bl]);
      acc1[bl] = fmaf(qq.z, w1[2], acc1[bl]);
      acc1[bl] = fmaf(qq.w, w1[3], acc1[bl]);
    }
  }
#pragma unroll
  for (int bl = 0; bl < 8; ++bl) {
    const size_t base = ((size_t)(bg * 8 + bl) * NH + h) * DM;
    qk1[base + e] = acc0[bl] * 0.125f;
    qk1[base + e + 256] = acc1[bl] * 0.125f;
  }
  if (tid < 8) {
    float s = 0.f;
    for (int d = 0; d < 64; ++d) s += q8[tid][d] * bk[h * 64 + d];
    qc1[(size_t)(bg * 8 + tid) * NH + h] = s * 0.125f;
  }
}

// ---------------------------------------------------------------------------
// Kernel B v3: one block per batch b; 8 waves = 2 head-halves x 4 t-chunks.
// Pointer-walk over contiguous prev rows (no per-t select/clamp address
// math); cur (t=199) row peeled as wave-uniform tail of chunk 3; prefetch
// distance 2 (3 rows in flight) for latency robustness at 4 waves/SIMD.
// ---------------------------------------------------------------------------
__global__ __launch_bounds__(512, 4) void attn_kernel(
    const float* __restrict__ cur, const float* __restrict__ prev,
    const float* __restrict__ mask, const float* __restrict__ qk1,
    const float* __restrict__ qc1, const float* __restrict__ Wv,
    const float* __restrict__ bv, float* __restrict__ out) {
  __shared__ float red[2][4][DM];  // [g][hl][e] staged ctx reduce, 16 KB
  __shared__ float lred[2][4][4];  // [g][c][hl] exp-sum partials
  const int tid = threadIdx.x;
  const int lane = tid & 63;
  const int wave = tid >> 6;
  const int g = wave & 1;   // head-half: heads [4g, 4g+4)
  const int c = wave >> 1;  // t-chunk: [50c, 50c+50)
  const int b = blockIdx.x;

  float4 ka[4], kb[4];
  float qc[4];
#pragma unroll
  for (int hl = 0; hl < 4; ++hl) {
    const float* kp = qk1 + ((size_t)b * NH + (g * 4 + hl)) * DM;
    ka[hl] = *(const float4*)(kp + 4 * lane);
    kb[hl] = *(const float4*)(kp + 256 + 4 * lane);
    qc[hl] = qc1[(size_t)b * NH + (g * 4 + hl)];
  }
  float4 cA[4], cB[4];
#pragma unroll
  for (int hl = 0; hl < 4; ++hl) {
    cA[hl] = make_float4(0.f, 0.f, 0.f, 0.f);
    cB[hl] = make_float4(0.f, 0.f, 0.f, 0.f);
  }
  float ls0 = 0.f, ls1 = 0.f, ls2 = 0.f, ls3 = 0.f;
  const int t0 = c * 50;
  // chunk 3 handles its last row (t=199 -> cur) as a peeled tail
  const int nrows = (c == 3) ? 49 : 50;
  // preload this chunk's mask values (lane l <-> t0+l), clamp tail lanes
  const int ml = (lane < 49) ? lane : 49;
  const float mreg = mask[(size_t)b * TT + t0 + ml];

#define ATTN_ROW(RA, RB, MIDX)                                         \
  {                                                                    \
    float pp[4];                                                       \
    _Pragma("unroll") for (int hl = 0; hl < 4; ++hl) pp[hl] =          \
        dot8(RA, RB, ka[hl], kb[hl]);                                  \
    _Pragma("unroll") for (int hl = 0; hl < 4; ++hl) pp[hl] =          \
        wred64(pp[hl]);                                                \
    const float mval = __shfl(mreg, (MIDX));                           \
    _Pragma("unroll") for (int hl = 0; hl < 4; ++hl) {                 \
      const float w = __expf(pp[hl] + qc[hl] + mval);                  \
      if (hl == 0) ls0 += w;                                           \
      if (hl == 1) ls1 += w;                                           \
      if (hl == 2) ls2 += w;                                           \
      if (hl == 3) ls3 += w;                                           \
      cA[hl].x = fmaf(w, RA.x, cA[hl].x);                              \
      cA[hl].y = fmaf(w, RA.y, cA[hl].y);                              \
      cA[hl].z = fmaf(w, RA.z, cA[hl].z);                              \
      cA[hl].w = fmaf(w, RA.w, cA[hl].w);                              \
      cB[hl].x = fmaf(w, RB.x, cB[hl].x);                              \
      cB[hl].y = fmaf(w, RB.y, cB[hl].y);                              \
      cB[hl].z = fmaf(w, RB.z, cB[hl].z);                              \
      cB[hl].w = fmaf(w, RB.w, cB[hl].w);                              \
    }                                                                  \
  }

  // contiguous row walk: row i at pa + i*DM
  const float* pa = prev + ((size_t)b * HIST + t0) * DM + 4 * lane;
  float4 r0a = *(const float4*)(pa);
  float4 r0b = *(const float4*)(pa + 256);
  float4 r1a = *(const float4*)(pa + DM);
  float4 r1b = *(const float4*)(pa + DM + 256);
  for (int i = 0; i < nrows; ++i) {
    int ip = i + 2;
    if (ip >= nrows) ip = nrows - 1;
    const float* np = pa + (size_t)ip * DM;
    const float4 q0a = *(const float4*)(np);
    const float4 q0b = *(const float4*)(np + 256);
    ATTN_ROW(r0a, r0b, i)
    r0a = r1a;
    r0b = r1b;
    r1a = q0a;
    r1b = q0b;
  }
  if (c == 3) {  // peeled t = 199 -> current row, mask index 49
    const float* cp = cur + (size_t)b * DM + 4 * lane;
    const float4 xa = *(const float4*)(cp);
    const float4 xb = *(const float4*)(cp + 256);
    ATTN_ROW(xa, xb, 49)
  }
#undef ATTN_ROW

  if (lane == 0) {
    lred[g][c][0] = ls0;
    lred[g][c][1] = ls1;
    lred[g][c][2] = ls2;
    lred[g][c][3] = ls3;
  }
  // Staged reduction over the 4 t-chunks into red[g][hl][e].
  for (int cc = 0; cc < 4; ++cc) {
    if (c == cc) {
#pragma unroll
      for (int hl = 0; hl < 4; ++hl) {
        float* dst = &red[g][hl][0];
        if (cc == 0) {
          *(float4*)(dst + 4 * lane) = cA[hl];
          *(float4*)(dst + 256 + 4 * lane) = cB[hl];
        } else {
          float4 o0 = *(const float4*)(dst + 4 * lane);
          float4 o1 = *(const float4*)(dst + 256 + 4 * lane);
          o0.x += cA[hl].x;
          o0.y += cA[hl].y;
          o0.z += cA[hl].z;
          o0.w += cA[hl].w;
          o1.x += cB[hl].x;
          o1.y += cB[hl].y;
          o1.z += cB[hl].z;
          o1.w += cB[hl].w;
          *(float4*)(dst + 4 * lane) = o0;
          *(float4*)(dst + 256 + 4 * lane) = o1;
        }
      }
    }
    __syncthreads();
  }
  // Out projection: wave hh -> head hh; softmax normalization deferred to
  // one scalar multiply at the end (linearity).
  const int hh = wave;
  const int g2 = hh >> 2, h2 = hh & 3;
  const float linv = 1.0f / (lred[g2][0][h2] + lred[g2][1][h2] +
                             lred[g2][2][h2] + lred[g2][3][h2]);
  const float4 na = *(const float4*)(&red[g2][h2][0] + 4 * lane);
  const float4 nb = *(const float4*)(&red[g2][h2][0] + 256 + 4 * lane);
  float keep = 0.f;
  for (int r = 0; r < 64; ++r) {
    const float* wvp = Wv + (size_t)(hh * 64 + r) * DM;
    const float4 wa = *(const float4*)(wvp + 4 * lane);
    const float4 wb = *(const float4*)(wvp + 256 + 4 * lane);
    float p = wred64(dot8(na, nb, wa, wb));
    if (lane == r) keep = p;
  }
  out[(size_t)b * DM + hh * 64 + lane] = keep * linv + bv[hh * 64 + lane];
}

extern "C" void kernel_launch(void* const* d_in, const int* in_sizes, int n_in,
                              void* d_out, int out_size, void* d_ws,
                              size_t ws_size, hipStream_t stream) {
  const float* cur = (const float*)d_in[0];   // [1024, 512]
  const float* prev = (const float*)d_in[1];  // [1024, 199, 512]
  const float* mask = (const float*)d_in[2];  // [1024, 200]
  const float* Wq = (const float*)d_in[3];    // [512, 512]
  const float* bq = (const float*)d_in[4];    // [512]
  const float* Wk = (const float*)d_in[5];
  const float* bk = (const float*)d_in[6];
  const float* Wv = (const float*)d_in[7];
  const float* bv = (const float*)d_in[8];
  float* out = (float*)d_out;  // [1024, 512] fp32

  // workspace: q [1024*512] | qk1 [1024*8*512] | qc1 [1024*8]  (~18.9 MB)
  float* q = (float*)d_ws;
  float* qk1 = q + (size_t)BS * DM;
  float* qc1 = qk1 + (size_t)BS * NH * DM;

  qproj_kernel<<<1024, 256, 0, stream>>>(cur, Wq, bq, q);
  qk_kernel<<<1024, 256, 0, stream>>>(q, Wk, bk, qk1, qc1);
  attn_kernel<<<1024, 512, 0, stream>>>(cur, prev, mask, qk1, qc1, Wv, bv, out);
}